// Round 1
// baseline (257.816 us; speedup 1.0000x reference)
//
#include <hip/hip_runtime.h>
#include <hip/hip_bf16.h>
#include <math.h>

// Problem constants (fixed by the reference): B=16, L=4096, N=512, D=256
#define BB 16
#define LL 4096
#define NN 512
#define DD 256

typedef __attribute__((ext_vector_type(8))) short  bf16x8; // MFMA A/B frag (8 bf16 = 4 VGPR)
typedef __attribute__((ext_vector_type(4))) float  f32x4;  // MFMA C/D frag
typedef __attribute__((ext_vector_type(4))) unsigned short u16x4;

__device__ __forceinline__ unsigned short f2bf(float x) {
    union { float f; unsigned u; } v; v.f = x;
    unsigned r = v.u + 0x7fffu + ((v.u >> 16) & 1u);   // RNE
    return (unsigned short)(r >> 16);
}

// LDS plan (134.4 KB total, 1 block/CU):
//  ps : pass1 = P chunk [128][256] bf16 row-major (n-major), swizzled
//       pass2 = P chunk transposed [256][128] bf16 (d-major), swizzled
//  xw : pass1 = X tile [64][256] bf16 (first 32KB), swizzled
//       pass2 = W tile [64][512] bf16 (whole 64KB), swizzled  (X dead by then)
struct __align__(16) Smem {
    char  ps[128 * 512];    // 64 KB
    char  xw[64 * 1024];    // 64 KB
    float xn[64];
    float pn[512];
    float redm[2][64];
    float reds[2][64];
};

__global__ __launch_bounds__(512) void cda_main(
    const float* __restrict__ X, const float* __restrict__ P,
    const int* __restrict__ lens, float* __restrict__ out)
{
    __shared__ Smem sm;

    // XCD-bijective swizzle: 1024 blocks, blockIdx%8 -> XCD, so each XCD owns 2 batches
    const int id = blockIdx.x;
    const int b  = (id & 7) * 2 + ((id >> 3) >> 6);
    const int lt = (id >> 3) & 63;
    const int l0 = lt * 64;

    const int tid  = threadIdx.x;
    const int w    = tid >> 6;      // wave 0..7
    const int lane = tid & 63;
    const int lo   = lane & 15;
    const int g    = lane >> 4;
    const int wm   = w >> 1;        // 4 row-groups of 16
    const int wn   = w & 1;         // 2 col-halves
    const int len  = lens[b];
    const int rowb = wm * 16 + g * 4;

    const float* Xb   = X + ((size_t)b * LL + l0) * DD;
    const float* Pb   = P + (size_t)b * NN * DD;
    float*       Eout = out + ((size_t)b * LL + l0) * DD;
    float*       Wout = out + (size_t)BB * LL * DD + ((size_t)b * LL + l0) * (size_t)NN;

    // ---- stage X tile (bf16, swizzled) + x-norms; wave w owns rows w*8..w*8+7 ----
    #pragma unroll
    for (int r = 0; r < 8; ++r) {
        const int row = w * 8 + r;
        const float4 v = *(const float4*)(Xb + row * DD + lane * 4);
        float ss = v.x * v.x + v.y * v.y + v.z * v.z + v.w * v.w;
        #pragma unroll
        for (int off = 32; off > 0; off >>= 1) ss += __shfl_xor(ss, off);
        if (lane == 0) sm.xn[row] = sqrtf(ss);
        u16x4 h; h.x = f2bf(v.x); h.y = f2bf(v.y); h.z = f2bf(v.z); h.w = f2bf(v.w);
        const int byte = (row * 512 + lane * 8) ^ ((row & 7) << 4);
        *(u16x4*)(sm.xw + byte) = h;
    }

    // ---- pass 1: S = X · P^T, 4 chunks of 128 profiles ----
    f32x4 acc[16];
    #pragma unroll
    for (int i = 0; i < 16; ++i) acc[i] = (f32x4){0.f, 0.f, 0.f, 0.f};

    #pragma unroll
    for (int c = 0; c < 4; ++c) {
        __syncthreads();                       // prev chunk readers done
        // stage chunk rows (wave w: local rows w*16..w*16+15) + p-norms
        #pragma unroll
        for (int rr = 0; rr < 16; ++rr) {
            const int nn = w * 16 + rr;
            const int n  = c * 128 + nn;
            const float4 v = *(const float4*)(Pb + n * DD + lane * 4);
            float ss = v.x * v.x + v.y * v.y + v.z * v.z + v.w * v.w;
            #pragma unroll
            for (int off = 32; off > 0; off >>= 1) ss += __shfl_xor(ss, off);
            if (lane == 0) sm.pn[n] = sqrtf(ss);
            u16x4 h; h.x = f2bf(v.x); h.y = f2bf(v.y); h.z = f2bf(v.z); h.w = f2bf(v.w);
            const int byte = (nn * 512 + lane * 8) ^ ((nn & 7) << 4);
            *(u16x4*)(sm.ps + byte) = h;
        }
        __syncthreads();
        // compute: 8 k-steps over D, wave covers rows wm*16+[0,16), chunk cols wn*64+[0,64)
        #pragma unroll
        for (int ks = 0; ks < 8; ++ks) {
            const int kk = ks * 32;
            const int arow = wm * 16 + lo;
            const bf16x8 a = *(const bf16x8*)(sm.xw +
                ((arow * 512 + (kk + g * 8) * 2) ^ ((arow & 7) << 4)));
            #pragma unroll
            for (int fi = 0; fi < 4; ++fi) {
                const int nl = wn * 64 + fi * 16 + lo;   // chunk-local profile idx
                const bf16x8 bb = *(const bf16x8*)(sm.ps +
                    ((nl * 512 + (kk + g * 8) * 2) ^ ((nl & 7) << 4)));
                acc[c * 4 + fi] = __builtin_amdgcn_mfma_f32_16x16x32_bf16(
                    a, bb, acc[c * 4 + fi], 0, 0, 0);
            }
        }
    }

    // ---- cosine scale + mask + softmax over N=512 ----
    float xnr[4];
    #pragma unroll
    for (int r = 0; r < 4; ++r) xnr[r] = sm.xn[rowb + r];

    float m4[4] = {-3.4028235e38f, -3.4028235e38f, -3.4028235e38f, -3.4028235e38f};
    #pragma unroll
    for (int c = 0; c < 4; ++c)
    #pragma unroll
    for (int fi = 0; fi < 4; ++fi) {
        const int col = c * 128 + wn * 64 + fi * 16 + lo;
        const float pnc = sm.pn[col];
        const bool msk = (col >= len);
        #pragma unroll
        for (int r = 0; r < 4; ++r) {
            const float den = fmaxf(xnr[r] * pnc, 1e-8f);
            float s = acc[c * 4 + fi][r] * __builtin_amdgcn_rcpf(den);
            s = msk ? -3.4028235e38f : s;
            acc[c * 4 + fi][r] = s;
            m4[r] = fmaxf(m4[r], s);
        }
    }
    // row max: butterfly within 16-lane group, then combine the two col-halves via LDS
    #pragma unroll
    for (int off = 1; off < 16; off <<= 1)
        #pragma unroll
        for (int r = 0; r < 4; ++r) m4[r] = fmaxf(m4[r], __shfl_xor(m4[r], off));
    if (lo == 0) {
        #pragma unroll
        for (int r = 0; r < 4; ++r) sm.redm[wn][rowb + r] = m4[r];
    }
    __syncthreads();
    #pragma unroll
    for (int r = 0; r < 4; ++r) m4[r] = fmaxf(sm.redm[0][rowb + r], sm.redm[1][rowb + r]);

    float s4[4] = {0.f, 0.f, 0.f, 0.f};
    #pragma unroll
    for (int c = 0; c < 4; ++c)
    #pragma unroll
    for (int fi = 0; fi < 4; ++fi)
        #pragma unroll
        for (int r = 0; r < 4; ++r) {
            const float p = __expf(acc[c * 4 + fi][r] - m4[r]); // masked -> exp(-3.4e38)=0
            acc[c * 4 + fi][r] = p;
            s4[r] += p;
        }
    #pragma unroll
    for (int off = 1; off < 16; off <<= 1)
        #pragma unroll
        for (int r = 0; r < 4; ++r) s4[r] += __shfl_xor(s4[r], off);
    if (lo == 0) {
        #pragma unroll
        for (int r = 0; r < 4; ++r) sm.reds[wn][rowb + r] = s4[r];
    }
    __syncthreads();
    float sinv[4];
    #pragma unroll
    for (int r = 0; r < 4; ++r)
        sinv[r] = __builtin_amdgcn_rcpf(sm.reds[0][rowb + r] + sm.reds[1][rowb + r]);

    // ---- pass 1.5: weights -> global fp32, and W bf16 -> LDS (over dead X buffer) ----
    #pragma unroll
    for (int c = 0; c < 4; ++c)
    #pragma unroll
    for (int fi = 0; fi < 4; ++fi) {
        const int col = c * 128 + wn * 64 + fi * 16 + lo;
        #pragma unroll
        for (int r = 0; r < 4; ++r) {
            const int row = rowb + r;
            const float wgt = acc[c * 4 + fi][r] * sinv[r];
            Wout[row * NN + col] = wgt;
            const int byte = (row * 1024 + col * 2) ^ ((row & 7) << 4);
            *(unsigned short*)(sm.xw + byte) = f2bf(wgt);
        }
    }

    // ---- pass 2: E = W · P, contraction over n; P restaged TRANSPOSED [d][nn] ----
    f32x4 e[8];
    #pragma unroll
    for (int i = 0; i < 8; ++i) e[i] = (f32x4){0.f, 0.f, 0.f, 0.f};

    for (int c = 0; c < 4; ++c) {
        __syncthreads();                        // prev chunk readers done; c=0: Ws ready
        // wave w transposes nn rows w*16..w*16+15 in quads of 4
        #pragma unroll
        for (int q = 0; q < 4; ++q) {
            const int nn0 = w * 16 + q * 4;
            const int n0  = c * 128 + nn0;
            #pragma unroll
            for (int dp = 0; dp < 4; ++dp) {
                const int d = dp * 64 + lane;
                const float a0 = Pb[(n0 + 0) * DD + d];
                const float a1 = Pb[(n0 + 1) * DD + d];
                const float a2 = Pb[(n0 + 2) * DD + d];
                const float a3 = Pb[(n0 + 3) * DD + d];
                u16x4 h; h.x = f2bf(a0); h.y = f2bf(a1); h.z = f2bf(a2); h.w = f2bf(a3);
                const int byte = (d * 256 + nn0 * 2) ^ ((d & 7) << 4);
                *(u16x4*)(sm.ps + byte) = h;
            }
        }
        __syncthreads();
        // wave covers rows wm*16+[0,16), d-cols wn*128+[0,128); 4 k-steps per chunk
        #pragma unroll
        for (int ks = 0; ks < 4; ++ks) {
            const int kk = ks * 32;
            const int arow = wm * 16 + lo;
            const bf16x8 a = *(const bf16x8*)(sm.xw +
                ((arow * 1024 + (c * 128 + kk + g * 8) * 2) ^ ((arow & 7) << 4)));
            #pragma unroll
            for (int df = 0; df < 8; ++df) {
                const int d = wn * 128 + df * 16 + lo;
                const bf16x8 bb = *(const bf16x8*)(sm.ps +
                    ((d * 256 + (kk + g * 8) * 2) ^ ((d & 7) << 4)));
                e[df] = __builtin_amdgcn_mfma_f32_16x16x32_bf16(a, bb, e[df], 0, 0, 0);
            }
        }
    }

    // ---- epilogue: write embedding ----
    #pragma unroll
    for (int df = 0; df < 8; ++df)
        #pragma unroll
        for (int r = 0; r < 4; ++r) {
            const int row = rowb + r;
            const int d = wn * 128 + df * 16 + lo;
            Eout[row * DD + d] = e[df][r];
        }
}

extern "C" void kernel_launch(void* const* d_in, const int* in_sizes, int n_in,
                              void* d_out, int out_size, void* d_ws, size_t ws_size,
                              hipStream_t stream) {
    const float* X    = (const float*)d_in[0];
    const float* P    = (const float*)d_in[1];
    const int*   lens = (const int*)d_in[2];
    float*       out  = (float*)d_out;
    hipLaunchKernelGGL(cda_main, dim3(1024), dim3(512), 0, stream, X, P, lens, out);
}

// Round 2
// 145.725 us; speedup vs baseline: 1.7692x; 1.7692x over previous
//
#include <hip/hip_runtime.h>
#include <hip/hip_bf16.h>
#include <math.h>

// Problem constants: B=16, L=4096, N=512, D=256
#define BB 16
#define LL 4096
#define NN 512
#define DD 256

typedef __attribute__((ext_vector_type(8))) short  bf16x8; // MFMA A/B frag
typedef __attribute__((ext_vector_type(4))) float  f32x4;  // MFMA C/D frag
typedef __attribute__((ext_vector_type(4))) unsigned short u16x4;

typedef __attribute__((address_space(1))) const void  gvoid_t;
typedef __attribute__((address_space(3))) void        lvoid_t;

__device__ __forceinline__ unsigned short f2bf(float x) {
    union { float f; unsigned u; } v; v.f = x;
    unsigned r = v.u + 0x7fffu + ((v.u >> 16) & 1u);   // RNE
    return (unsigned short)(r >> 16);
}

// ---------------- prologue: x-norms + pre-normalized/pre-swizzled P images ----
// pnI: per (b, chunk c of 32 n): 16KB tile, addr = (nl*512 + d*2) ^ ((nl&7)<<4), value = bf16(p/||p||)
// ptI: per (b, c):               16KB tile, addr = (d*64  + nl*2) ^ ((d&15)<<4), value = bf16(p) raw
__global__ __launch_bounds__(256) void cda_prep(
    const float* __restrict__ X, const float* __restrict__ P,
    float* __restrict__ xnorm, char* __restrict__ pnI, char* __restrict__ ptI)
{
    const int gw   = (int)((blockIdx.x * 256 + threadIdx.x) >> 6); // global wave id
    const int lane = threadIdx.x & 63;

    if (gw < BB * LL) {                       // X row norms
        const float4 v = *(const float4*)(X + (size_t)gw * DD + lane * 4);
        float ss = v.x * v.x + v.y * v.y + v.z * v.z + v.w * v.w;
        #pragma unroll
        for (int off = 32; off > 0; off >>= 1) ss += __shfl_xor(ss, off);
        if (lane == 0) xnorm[gw] = sqrtf(ss);
    } else {                                  // P rows -> two swizzled bf16 images
        const int rr = gw - BB * LL;          // b*512 + n
        const float4 v = *(const float4*)(P + (size_t)rr * DD + lane * 4);
        float ss = v.x * v.x + v.y * v.y + v.z * v.z + v.w * v.w;
        #pragma unroll
        for (int off = 32; off > 0; off >>= 1) ss += __shfl_xor(ss, off);
        const float rinv = 1.0f / sqrtf(ss);
        const int n  = rr & (NN - 1);
        const int c  = n >> 5;
        const int nl = n & 31;
        const size_t tile = ((size_t)(rr >> 9) * 16 + c) * 16384;
        // normalized row-major image (for S-GEMM B-frags)
        u16x4 h;
        h.x = f2bf(v.x * rinv); h.y = f2bf(v.y * rinv);
        h.z = f2bf(v.z * rinv); h.w = f2bf(v.w * rinv);
        *(u16x4*)(pnI + tile + ((nl * 512 + lane * 8) ^ ((nl & 7) << 4))) = h;
        // raw transposed image (for E-GEMM B-frags)
        const float raw[4] = {v.x, v.y, v.z, v.w};
        #pragma unroll
        for (int j = 0; j < 4; ++j) {
            const int d = lane * 4 + j;
            *(unsigned short*)(ptI + tile + ((d * 64 + nl * 2) ^ ((d & 15) << 4))) = f2bf(raw[j]);
        }
    }
}

// ---------------- main fused kernel --------------------------------------
// 64 L-rows per block, 512 threads (8 waves: 4 wm x 2 wn), 16 chunks of 32 n.
// Single pass: per chunk  S=Xhat·Pnhat^T -> p=exp(S) (no max needed, |s|<=1)
//              -> wc(bf16) -> E += wc·Pt.  Final: scale by 1/sum, write W & E.
struct __align__(16) Smem {
    char  xh[32768];      // [64 l][256 d] bf16, ^((l&7)<<4)
    char  pn[16384];      // chunk image (linear copy of pre-swizzled global)
    char  pt[16384];      // chunk image (linear copy of pre-swizzled global)
    char  wc[4096];       // [64 l][32 n] bf16, ^((l&15)<<4)
    float red[2][64];
};

__global__ __launch_bounds__(512, 4) void cda_main(
    const float* __restrict__ X, const char* __restrict__ pnI,
    const char* __restrict__ ptI, const float* __restrict__ xnorm,
    const int* __restrict__ lens, float* __restrict__ out)
{
    __shared__ Smem sm;

    // XCD-bijective swizzle: 1024 blocks, id&7 -> XCD, each XCD owns 2 batches
    const int id = blockIdx.x;
    const int b  = (id & 7) * 2 + ((id >> 3) >> 6);
    const int lt = (id >> 3) & 63;
    const int l0 = lt * 64;

    const int tid  = threadIdx.x;
    const int w    = tid >> 6;
    const int lane = tid & 63;
    const int lo   = lane & 15;
    const int g    = lane >> 4;
    const int wm   = w >> 1;
    const int wn   = w & 1;
    const int len  = lens[b];
    const int rowb = wm * 16 + g * 4;
    const int nl   = wn * 16 + lo;      // chunk-local profile col
    const int arow = wm * 16 + lo;      // A-frag row

    const float* Xb  = X + ((size_t)b * LL + l0) * DD;
    const char*  PnB = pnI + (size_t)b * 262144;
    const char*  PtB = ptI + (size_t)b * 262144;

    // ---- stage normalized X tile (bf16, swizzled); xnorm precomputed ----
    #pragma unroll
    for (int r = 0; r < 8; ++r) {
        const int row = w * 8 + r;
        const float4 v = *(const float4*)(Xb + row * DD + lane * 4);
        const float inv = 1.0f / xnorm[(size_t)b * LL + l0 + row];
        u16x4 h;
        h.x = f2bf(v.x * inv); h.y = f2bf(v.y * inv);
        h.z = f2bf(v.z * inv); h.w = f2bf(v.w * inv);
        *(u16x4*)(sm.xh + ((row * 512 + lane * 8) ^ ((row & 7) << 4))) = h;
    }

    f32x4 e[8];
    #pragma unroll
    for (int i = 0; i < 8; ++i) e[i] = (f32x4){0.f, 0.f, 0.f, 0.f};
    unsigned pm[16][2];                 // packed bf16 p, statically indexed
    float s4[4] = {0.f, 0.f, 0.f, 0.f};

    #pragma unroll
    for (int c = 0; c < 16; ++c) {
        __syncthreads();                // prior chunk's pn/pt/wc readers done
        // ---- stage chunk images via global_load_lds (16B/lane) ----
        {
            const char* gsrc; char* ldst;
            if (w < 4) { gsrc = PnB + c * 16384 + w * 4096;       ldst = sm.pn + w * 4096; }
            else       { gsrc = PtB + c * 16384 + (w - 4) * 4096; ldst = sm.pt + (w - 4) * 4096; }
            #pragma unroll
            for (int q = 0; q < 4; ++q) {
                __builtin_amdgcn_global_load_lds(
                    (gvoid_t*)(gsrc + q * 1024 + lane * 16),
                    (lvoid_t*)(ldst + q * 1024), 16, 0, 0);
            }
        }
        __syncthreads();                // staged data visible

        // ---- S chunk: 8 k-steps over D=256 ----
        f32x4 acc = (f32x4){0.f, 0.f, 0.f, 0.f};
        #pragma unroll
        for (int ks = 0; ks < 8; ++ks) {
            const bf16x8 a = *(const bf16x8*)(sm.xh +
                ((arow * 512 + ks * 64 + g * 16) ^ ((arow & 7) << 4)));
            const bf16x8 bb = *(const bf16x8*)(sm.pn +
                ((nl * 512 + ks * 64 + g * 16) ^ ((nl & 7) << 4)));
            acc = __builtin_amdgcn_mfma_f32_16x16x32_bf16(a, bb, acc, 0, 0, 0);
        }

        // ---- p = exp(cos-sim), masked; keep packed in regs + stash to wc ----
        const bool valid = (c * 32 + nl) < len;
        unsigned short pw[4];
        #pragma unroll
        for (int r = 0; r < 4; ++r) {
            const float p = valid ? __expf(acc[r]) : 0.f;
            s4[r] += p;
            pw[r] = f2bf(p);
        }
        pm[c][0] = (unsigned)pw[0] | ((unsigned)pw[1] << 16);
        pm[c][1] = (unsigned)pw[2] | ((unsigned)pw[3] << 16);
        #pragma unroll
        for (int r = 0; r < 4; ++r) {
            const int l = rowb + r;
            *(unsigned short*)(sm.wc + ((l * 64 + nl * 2) ^ ((l & 15) << 4))) = pw[r];
        }
        __syncthreads();                // wc complete

        // ---- E += wc · Pt  (k = 32 chunk profiles) ----
        const bf16x8 a2 = *(const bf16x8*)(sm.wc +
            ((arow * 64 + g * 16) ^ ((arow & 15) << 4)));
        #pragma unroll
        for (int df = 0; df < 8; ++df) {
            const int d = wn * 128 + df * 16 + lo;
            const bf16x8 b2 = *(const bf16x8*)(sm.pt +
                ((d * 64 + g * 16) ^ ((d & 15) << 4)));
            e[df] = __builtin_amdgcn_mfma_f32_16x16x32_bf16(a2, b2, e[df], 0, 0, 0);
        }
    }

    // ---- row sums -> 1/sum ----
    #pragma unroll
    for (int off = 1; off < 16; off <<= 1)
        #pragma unroll
        for (int r = 0; r < 4; ++r) s4[r] += __shfl_xor(s4[r], off);
    if (lo == 0) {
        #pragma unroll
        for (int r = 0; r < 4; ++r) sm.red[wn][rowb + r] = s4[r];
    }
    __syncthreads();
    float sinv[4];
    #pragma unroll
    for (int r = 0; r < 4; ++r)
        sinv[r] = 1.0f / (sm.red[0][rowb + r] + sm.red[1][rowb + r]);

    // ---- write weights (fp32) from packed regs ----
    float* Wout = out + (size_t)BB * LL * DD + ((size_t)b * LL + l0) * (size_t)NN;
    #pragma unroll
    for (int c = 0; c < 16; ++c) {
        const int col = c * 32 + nl;
        const float p0 = __uint_as_float(pm[c][0] << 16);
        const float p1 = __uint_as_float(pm[c][0] & 0xffff0000u);
        const float p2 = __uint_as_float(pm[c][1] << 16);
        const float p3 = __uint_as_float(pm[c][1] & 0xffff0000u);
        Wout[(size_t)(rowb + 0) * NN + col] = p0 * sinv[0];
        Wout[(size_t)(rowb + 1) * NN + col] = p1 * sinv[1];
        Wout[(size_t)(rowb + 2) * NN + col] = p2 * sinv[2];
        Wout[(size_t)(rowb + 3) * NN + col] = p3 * sinv[3];
    }

    // ---- write embedding ----
    float* Eout = out + ((size_t)b * LL + l0) * DD;
    #pragma unroll
    for (int df = 0; df < 8; ++df)
        #pragma unroll
        for (int r = 0; r < 4; ++r)
            Eout[(size_t)(rowb + r) * DD + wn * 128 + df * 16 + lo] = e[df][r] * sinv[r];
}

extern "C" void kernel_launch(void* const* d_in, const int* in_sizes, int n_in,
                              void* d_out, int out_size, void* d_ws, size_t ws_size,
                              hipStream_t stream) {
    const float* X    = (const float*)d_in[0];
    const float* P    = (const float*)d_in[1];
    const int*   lens = (const int*)d_in[2];
    float*       out  = (float*)d_out;

    // workspace layout: xnorm (256KB) | pnI (4MB) | ptI (4MB)  -> 8.5 MB
    float* xnorm = (float*)d_ws;
    char*  pnI   = (char*)d_ws + 262144;
    char*  ptI   = (char*)d_ws + 262144 + 4194304;

    const int prep_waves  = BB * LL + BB * NN;          // 73728
    const int prep_blocks = prep_waves * 64 / 256;      // 18432
    hipLaunchKernelGGL(cda_prep, dim3(prep_blocks), dim3(256), 0, stream,
                       X, P, xnorm, pnI, ptI);
    hipLaunchKernelGGL(cda_main, dim3(1024), dim3(512), 0, stream,
                       X, pnI, ptI, xnorm, lens, out);
}

// Round 3
// 102.070 us; speedup vs baseline: 2.5259x; 1.4277x over previous
//
#include <hip/hip_runtime.h>
#include <hip/hip_bf16.h>
#include <math.h>

// Problem constants: B=16, L=4096, N=512, D=256
#define BB 16
#define LL 4096
#define NN 512
#define DD 256

typedef __attribute__((ext_vector_type(8))) short  bf16x8; // MFMA A/B frag
typedef __attribute__((ext_vector_type(4))) float  f32x4;  // MFMA C/D frag
typedef __attribute__((ext_vector_type(4))) unsigned short u16x4;

typedef __attribute__((address_space(1))) const void  gvoid_t;
typedef __attribute__((address_space(3))) void        lvoid_t;

__device__ __forceinline__ unsigned short f2bf(float x) {
    union { float f; unsigned u; } v; v.f = x;
    unsigned r = v.u + 0x7fffu + ((v.u >> 16) & 1u);   // RNE
    return (unsigned short)(r >> 16);
}
__device__ __forceinline__ float bfhi(unsigned u) { return __uint_as_float(u & 0xffff0000u); }
__device__ __forceinline__ float bflo(unsigned u) { return __uint_as_float(u << 16); }

// ---------------- prologue kernel: P -> two pre-swizzled bf16 images -------
// Per (b, chunk c of 32 n), 16KB tiles:
//  pn: normalized rows, addr (nl*512 + d*2) ^ ((nl&7)<<4)        [S A-frags]
//  pe: raw, n-permuted transpose: kslot(nl) = ((nl>>2)&3)*8 + ((nl>>4)<<2) + (nl&3)
//      addr (d*64 + kslot*2) ^ ((d&15)<<4)                       [E B-frags]
__global__ __launch_bounds__(256) void cda_prep(
    const float* __restrict__ P, char* __restrict__ pnI, char* __restrict__ peI)
{
    const int gw   = blockIdx.x * 4 + (threadIdx.x >> 6);   // P row: b*512 + n
    const int lane = threadIdx.x & 63;
    const float4 v = *(const float4*)(P + (size_t)gw * DD + lane * 4);
    float ss = v.x * v.x + v.y * v.y + v.z * v.z + v.w * v.w;
    #pragma unroll
    for (int off = 32; off > 0; off >>= 1) ss += __shfl_xor(ss, off);
    const float rinv = 1.0f / sqrtf(ss);
    const int n  = gw & (NN - 1);
    const int nl = n & 31;
    const size_t tile = ((size_t)((gw >> 9) * 16 + (n >> 5))) << 14;

    u16x4 h;
    h.x = f2bf(v.x * rinv); h.y = f2bf(v.y * rinv);
    h.z = f2bf(v.z * rinv); h.w = f2bf(v.w * rinv);
    *(u16x4*)(pnI + tile + ((nl * 512 + lane * 8) ^ ((nl & 7) << 4))) = h;

    const int ks = ((nl >> 2) & 3) * 8 + ((nl >> 4) << 2) + (nl & 3);
    const float raw[4] = {v.x, v.y, v.z, v.w};
    #pragma unroll
    for (int j = 0; j < 4; ++j) {
        const int d = lane * 4 + j;
        *(unsigned short*)(peI + tile + ((d * 64 + ks * 2) ^ ((d & 15) << 4))) = f2bf(raw[j]);
    }
}

// ---------------- main kernel ---------------------------------------------
// 256 threads (4 waves), 64 L-rows/block, 16 chunks of 32 n.
// Wave w owns l-rows w*16..w*16+15 and full D. Swapped S-mfma keeps p lane-local:
// thread (lo,g) holds W[l=lo][n = c*32 + nh*16 + g*4 + r] -> direct E A-frag.
struct __align__(16) Smem {
    union {
        struct { char pn[2][16384]; char pe[2][16384]; } img;   // double-buffered images
        char xstage[32768];                                     // transient X staging
    } u;
    float wtile[64 * 36];   // padded W coalescing tile (stride 36 breaks bank aliasing)
    float tbl[64];          // per-row 1/sum broadcast
};

__global__ __launch_bounds__(256, 2) void cda_main(
    const float* __restrict__ X, const char* __restrict__ pnI,
    const char* __restrict__ peI, const int* __restrict__ lens,
    float* __restrict__ out)
{
    __shared__ Smem sm;

    const int id = blockIdx.x;
    const int b  = (id & 7) * 2 + (id >> 9);   // XCD-bijective: 2 batches per XCD
    const int l0 = ((id >> 3) & 63) * 64;

    const int tid  = threadIdx.x;
    const int w    = tid >> 6;
    const int lane = tid & 63;
    const int lo   = lane & 15;
    const int g    = lane >> 4;
    const int len  = lens[b];

    const float* Xb  = X + ((size_t)b * LL + l0) * DD;
    const char*  pnB = pnI + (size_t)b * 262144;
    const char*  peB = peI + (size_t)b * 262144;

    // ---- stage X tile: fp32 -> normalized bf16, swizzled (norms inline) ----
    #pragma unroll
    for (int rr = 0; rr < 16; ++rr) {
        const int row = w * 16 + rr;
        const float4 v = *(const float4*)(Xb + row * DD + lane * 4);
        float ss = v.x * v.x + v.y * v.y + v.z * v.z + v.w * v.w;
        #pragma unroll
        for (int off = 32; off > 0; off >>= 1) ss += __shfl_xor(ss, off);
        const float inv = 1.0f / sqrtf(ss);
        u16x4 h;
        h.x = f2bf(v.x * inv); h.y = f2bf(v.y * inv);
        h.z = f2bf(v.z * inv); h.w = f2bf(v.w * inv);
        *(u16x4*)(sm.u.xstage + ((row * 512 + lane * 8) ^ ((row & 7) << 4))) = h;
    }
    __syncthreads();
    // X-hat fragments to registers (B-operand of swapped S-mfma)
    bf16x8 xf[8];
    #pragma unroll
    for (int ks = 0; ks < 8; ++ks)
        xf[ks] = *(const bf16x8*)(sm.u.xstage +
            (((w * 16 + lo) * 512 + ks * 64 + g * 16) ^ ((lo & 7) << 4)));
    __syncthreads();   // xstage dead; image buffers may now be DMA'd

    // ---- prologue: stage chunk 0 images ----
    #pragma unroll
    for (int q = 0; q < 4; ++q)
        __builtin_amdgcn_global_load_lds((gvoid_t*)(pnB + q * 4096 + tid * 16),
                                         (lvoid_t*)(sm.u.img.pn[0] + q * 4096 + tid * 16), 16, 0, 0);
    #pragma unroll
    for (int q = 0; q < 4; ++q)
        __builtin_amdgcn_global_load_lds((gvoid_t*)(peB + q * 4096 + tid * 16),
                                         (lvoid_t*)(sm.u.img.pe[0] + q * 4096 + tid * 16), 16, 0, 0);

    f32x4 e[16];
    #pragma unroll
    for (int i = 0; i < 16; ++i) e[i] = (f32x4){0.f, 0.f, 0.f, 0.f};
    unsigned pm[16][4];
    float ssum = 0.f;

    #pragma unroll
    for (int c = 0; c < 16; ++c) {
        const int pb = c & 1;
        asm volatile("s_waitcnt vmcnt(0)" ::: "memory");   // this chunk's images landed
        __builtin_amdgcn_s_barrier();                      // visible to all waves; prev readers done
        __builtin_amdgcn_sched_barrier(0);
        if (c < 15) {                                      // prefetch next chunk into other buffer
            const char* pnT = pnB + (c + 1) * 16384;
            const char* peT = peB + (c + 1) * 16384;
            char* pnD = sm.u.img.pn[pb ^ 1];
            char* peD = sm.u.img.pe[pb ^ 1];
            #pragma unroll
            for (int q = 0; q < 4; ++q)
                __builtin_amdgcn_global_load_lds((gvoid_t*)(pnT + q * 4096 + tid * 16),
                                                 (lvoid_t*)(pnD + q * 4096 + tid * 16), 16, 0, 0);
            #pragma unroll
            for (int q = 0; q < 4; ++q)
                __builtin_amdgcn_global_load_lds((gvoid_t*)(peT + q * 4096 + tid * 16),
                                                 (lvoid_t*)(peD + q * 4096 + tid * 16), 16, 0, 0);
        }

        // ---- S^T: thread (lo,g) accumulates S[l=lo][n = nh*16 + g*4 + r] ----
        const char* pnL = sm.u.img.pn[pb];
        f32x4 a0 = (f32x4){0.f, 0.f, 0.f, 0.f};
        f32x4 a1 = (f32x4){0.f, 0.f, 0.f, 0.f};
        #pragma unroll
        for (int ks = 0; ks < 8; ++ks) {
            const bf16x8 f0 = *(const bf16x8*)(pnL +
                ((lo * 512 + ks * 64 + g * 16) ^ ((lo & 7) << 4)));
            a0 = __builtin_amdgcn_mfma_f32_16x16x32_bf16(f0, xf[ks], a0, 0, 0, 0);
            const bf16x8 f1 = *(const bf16x8*)(pnL +
                (((16 + lo) * 512 + ks * 64 + g * 16) ^ ((lo & 7) << 4)));
            a1 = __builtin_amdgcn_mfma_f32_16x16x32_bf16(f1, xf[ks], a1, 0, 0, 0);
        }

        // ---- p = exp(sim) (|sim|<=1 -> no max pass), mask, pack ----
        unsigned short pw[8];
        #pragma unroll
        for (int r = 0; r < 4; ++r) {
            const int n0 = c * 32 + g * 4 + r;
            const float p0 = (n0 < len) ? __expf(a0[r]) : 0.f;
            ssum += p0; pw[r] = f2bf(p0);
            const float p1 = (n0 + 16 < len) ? __expf(a1[r]) : 0.f;
            ssum += p1; pw[4 + r] = f2bf(p1);
        }
        pm[c][0] = (unsigned)pw[0] | ((unsigned)pw[1] << 16);
        pm[c][1] = (unsigned)pw[2] | ((unsigned)pw[3] << 16);
        pm[c][2] = (unsigned)pw[4] | ((unsigned)pw[5] << 16);
        pm[c][3] = (unsigned)pw[6] | ((unsigned)pw[7] << 16);

        // ---- E += p-frag · pe  (contraction over the 32 chunk profiles) ----
        union { unsigned u[4]; bf16x8 v; } pf;
        pf.u[0] = pm[c][0]; pf.u[1] = pm[c][1]; pf.u[2] = pm[c][2]; pf.u[3] = pm[c][3];
        const char* peL = sm.u.img.pe[pb];
        #pragma unroll
        for (int df = 0; df < 16; ++df) {
            const bf16x8 bf = *(const bf16x8*)(peL +
                (((df * 16 + lo) * 64 + g * 16) ^ (lo << 4)));
            e[df] = __builtin_amdgcn_mfma_f32_16x16x32_bf16(pf.v, bf, e[df], 0, 0, 0);
        }
    }

    // ---- row sums: thread's ssum covers row (w*16+lo), its g-share of n ----
    ssum += __shfl_xor(ssum, 16);
    ssum += __shfl_xor(ssum, 32);
    const float sinv = 1.0f / ssum;
    if (g == 0) sm.tbl[w * 16 + lo] = sinv;

    // ---- W epilogue: 16 rounds through padded LDS tile -> full-line stores ----
    float* Wout = out + (size_t)BB * LL * DD + ((size_t)b * LL + l0) * (size_t)NN;
    #pragma unroll
    for (int c = 0; c < 16; ++c) {
        float4 v0, v1;
        v0.x = bflo(pm[c][0]) * sinv; v0.y = bfhi(pm[c][0]) * sinv;
        v0.z = bflo(pm[c][1]) * sinv; v0.w = bfhi(pm[c][1]) * sinv;
        v1.x = bflo(pm[c][2]) * sinv; v1.y = bfhi(pm[c][2]) * sinv;
        v1.z = bflo(pm[c][3]) * sinv; v1.w = bfhi(pm[c][3]) * sinv;
        char* base = (char*)sm.wtile + (size_t)(w * 16 + lo) * 144 + g * 16;
        *(float4*)(base)      = v0;   // cols g*4+r       (nh=0)
        *(float4*)(base + 64) = v1;   // cols 16+g*4+r    (nh=1)
        asm volatile("s_waitcnt lgkmcnt(0)" ::: "memory");
        __builtin_amdgcn_s_barrier();
        #pragma unroll
        for (int i = 0; i < 2; ++i) {
            const int slot = tid + 256 * i;
            const int row = slot >> 3, grp = slot & 7;
            const float4 t = *(const float4*)((char*)sm.wtile + (size_t)row * 144 + grp * 16);
            *(float4*)(Wout + (size_t)(l0 ? 0 : 0) + (size_t)row * NN + c * 32 + grp * 4) = t;
        }
        asm volatile("s_waitcnt lgkmcnt(0)" ::: "memory");
        __builtin_amdgcn_s_barrier();
    }

    // ---- E epilogue: per-wave transpose through dead pe[0], full-row stores ----
    float t4[4];
    #pragma unroll
    for (int r = 0; r < 4; ++r) t4[r] = sm.tbl[w * 16 + g * 4 + r];
    char* scr = sm.u.img.pe[0] + w * 4096;
    float* Eout = out + ((size_t)b * LL + l0 + w * 16) * DD;
    #pragma unroll
    for (int r = 0; r < 4; ++r) {
        #pragma unroll
        for (int df = 0; df < 16; ++df)
            *(float*)(scr + g * 1024 + (size_t)(df * 16 + lo) * 4) = e[df][r] * t4[r];
        #pragma unroll
        for (int it = 0; it < 4; ++it) {
            const float4 t = *(const float4*)(scr + it * 1024 + lane * 16);
            *(float4*)(Eout + (size_t)(it * 4 + r) * DD + lane * 4) = t;
        }
    }
}

extern "C" void kernel_launch(void* const* d_in, const int* in_sizes, int n_in,
                              void* d_out, int out_size, void* d_ws, size_t ws_size,
                              hipStream_t stream) {
    const float* X    = (const float*)d_in[0];
    const float* P    = (const float*)d_in[1];
    const int*   lens = (const int*)d_in[2];
    float*       out  = (float*)d_out;

    // workspace: pnI (4MB) | peI (4MB)
    char* pnI = (char*)d_ws;
    char* peI = (char*)d_ws + 4194304;

    hipLaunchKernelGGL(cda_prep, dim3(BB * NN / 4), dim3(256), 0, stream, P, pnI, peI);
    hipLaunchKernelGGL(cda_main, dim3(1024), dim3(256), 0, stream, X, pnI, peI, lens, out);
}

// Round 4
// 96.404 us; speedup vs baseline: 2.6743x; 1.0588x over previous
//
#include <hip/hip_runtime.h>
#include <hip/hip_bf16.h>
#include <math.h>

// Problem constants: B=16, L=4096, N=512, D=256
#define BB 16
#define LL 4096
#define NN 512
#define DD 256

typedef __attribute__((ext_vector_type(8))) short  bf16x8; // MFMA A/B frag
typedef __attribute__((ext_vector_type(4))) float  f32x4;  // MFMA C/D frag
typedef __attribute__((ext_vector_type(4))) unsigned short u16x4;

typedef __attribute__((address_space(1))) const void  gvoid_t;
typedef __attribute__((address_space(3))) void        lvoid_t;

#define GLL16(src, dst) __builtin_amdgcn_global_load_lds((gvoid_t*)(src), (lvoid_t*)(dst), 16, 0, 0)

__device__ __forceinline__ unsigned short f2bf(float x) {
    union { float f; unsigned u; } v; v.f = x;
    unsigned r = v.u + 0x7fffu + ((v.u >> 16) & 1u);   // RNE
    return (unsigned short)(r >> 16);
}
__device__ __forceinline__ float bfhi(unsigned u) { return __uint_as_float(u & 0xffff0000u); }
__device__ __forceinline__ float bflo(unsigned u) { return __uint_as_float(u << 16); }

// ---------------- prologue kernel: P -> two pre-swizzled bf16 images -------
// Per (b, chunk c of 32 n), 16KB tiles:
//  pn: normalized rows, addr (nl*512 + d*2) ^ ((nl&7)<<4)        [S A-frags]
//  pe: raw, n-permuted transpose: kslot(nl) = ((nl>>2)&3)*8 + ((nl>>4)<<2) + (nl&3)
//      addr (d*64 + kslot*2) ^ ((d&15)<<4)                       [E B-frags]
__global__ __launch_bounds__(256) void cda_prep(
    const float* __restrict__ P, char* __restrict__ pnI, char* __restrict__ peI)
{
    const int gw   = blockIdx.x * 4 + (threadIdx.x >> 6);   // P row: b*512 + n
    const int lane = threadIdx.x & 63;
    const float4 v = *(const float4*)(P + (size_t)gw * DD + lane * 4);
    float ss = v.x * v.x + v.y * v.y + v.z * v.z + v.w * v.w;
    #pragma unroll
    for (int off = 32; off > 0; off >>= 1) ss += __shfl_xor(ss, off);
    const float rinv = 1.0f / sqrtf(ss);
    const int n  = gw & (NN - 1);
    const int nl = n & 31;
    const size_t tile = ((size_t)((gw >> 9) * 16 + (n >> 5))) << 14;

    u16x4 h;
    h.x = f2bf(v.x * rinv); h.y = f2bf(v.y * rinv);
    h.z = f2bf(v.z * rinv); h.w = f2bf(v.w * rinv);
    *(u16x4*)(pnI + tile + ((nl * 512 + lane * 8) ^ ((nl & 7) << 4))) = h;

    const int ks = ((nl >> 2) & 3) * 8 + ((nl >> 4) << 2) + (nl & 3);
    const float raw[4] = {v.x, v.y, v.z, v.w};
    #pragma unroll
    for (int j = 0; j < 4; ++j) {
        const int d = lane * 4 + j;
        *(unsigned short*)(peI + tile + ((d * 64 + ks * 2) ^ ((d & 15) << 4))) = f2bf(raw[j]);
    }
}

// ---------------- main kernel ---------------------------------------------
// 256 threads (4 waves), 64 L-rows/block (wave w owns rows w*16..w*16+15).
// Phase S: 16 chunks, stage pn only, swapped S-mfma -> p lane-local, pm regs.
// Phase E: 16 chunks, stage pe only, W float4 stores interleaved with E-mfma.
struct __align__(16) Smem {
    char pn[2][16384];            // S-phase double buffer; E-epilogue scratch
    union {
        char xstage[32768];       // transient X staging
        char pe[2][16384];        // E-phase double buffer
    } u;
    float tbl[64];                // per-row 1/sum broadcast
};

__global__ __launch_bounds__(256, 2) void cda_main(
    const float* __restrict__ X, const char* __restrict__ pnI,
    const char* __restrict__ peI, const int* __restrict__ lens,
    float* __restrict__ out)
{
    __shared__ Smem sm;

    const int id = blockIdx.x;
    const int b  = (id & 7) * 2 + (id >> 9);   // XCD-bijective: 2 batches per XCD
    const int l0 = ((id >> 3) & 63) * 64;

    const int tid  = threadIdx.x;
    const int w    = tid >> 6;
    const int lane = tid & 63;
    const int lo   = lane & 15;
    const int g    = lane >> 4;
    const int len  = lens[b];

    const float* Xb  = X + ((size_t)b * LL + l0) * DD;
    const char*  pnB = pnI + (size_t)b * 262144;
    const char*  peB = peI + (size_t)b * 262144;

    // ---- prefetch chunk-0 pn immediately ----
    #pragma unroll
    for (int q = 0; q < 4; ++q)
        GLL16(pnB + q * 4096 + tid * 16, (char*)sm.pn[0] + q * 4096 + tid * 16);

    // ---- stage X tile: fp32 -> normalized bf16, swizzled (norms inline) ----
    #pragma unroll
    for (int rr = 0; rr < 16; ++rr) {
        const int row = w * 16 + rr;
        const float4 v = *(const float4*)(Xb + row * DD + lane * 4);
        float ss = v.x * v.x + v.y * v.y + v.z * v.z + v.w * v.w;
        #pragma unroll
        for (int off = 32; off > 0; off >>= 1) ss += __shfl_xor(ss, off);
        const float inv = 1.0f / sqrtf(ss);
        u16x4 h;
        h.x = f2bf(v.x * inv); h.y = f2bf(v.y * inv);
        h.z = f2bf(v.z * inv); h.w = f2bf(v.w * inv);
        *(u16x4*)(sm.u.xstage + ((row * 512 + lane * 8) ^ ((row & 7) << 4))) = h;
    }
    __syncthreads();
    bf16x8 xf[8];                               // X-hat B-frags, registers
    #pragma unroll
    for (int ks = 0; ks < 8; ++ks)
        xf[ks] = *(const bf16x8*)(sm.u.xstage +
            (((w * 16 + lo) * 512 + ks * 64 + g * 16) ^ ((lo & 7) << 4)));
    __syncthreads();                            // xstage dead -> pe area free

    // ---- prefetch chunk-0 pe (lands during S-phase) ----
    #pragma unroll
    for (int q = 0; q < 4; ++q)
        GLL16(peB + q * 4096 + tid * 16, (char*)sm.u.pe[0] + q * 4096 + tid * 16);

    unsigned pm[16][4];
    float ssum = 0.f;

    // ================= S phase =================
    #pragma unroll
    for (int c = 0; c < 16; ++c) {
        asm volatile("s_waitcnt vmcnt(0)" ::: "memory");   // pn[c] landed
        __builtin_amdgcn_s_barrier();
        __builtin_amdgcn_sched_barrier(0);
        if (c < 15) {
            const char* src = pnB + (c + 1) * 16384;
            char* dst = (char*)sm.pn[(c + 1) & 1];
            #pragma unroll
            for (int q = 0; q < 4; ++q)
                GLL16(src + q * 4096 + tid * 16, dst + q * 4096 + tid * 16);
        }
        const char* pnL = (const char*)sm.pn[c & 1];
        f32x4 a0 = (f32x4){0.f, 0.f, 0.f, 0.f};
        f32x4 a1 = (f32x4){0.f, 0.f, 0.f, 0.f};
        #pragma unroll
        for (int ks = 0; ks < 8; ++ks) {
            const bf16x8 f0 = *(const bf16x8*)(pnL +
                ((lo * 512 + ks * 64 + g * 16) ^ ((lo & 7) << 4)));
            a0 = __builtin_amdgcn_mfma_f32_16x16x32_bf16(f0, xf[ks], a0, 0, 0, 0);
            const bf16x8 f1 = *(const bf16x8*)(pnL +
                (((16 + lo) * 512 + ks * 64 + g * 16) ^ ((lo & 7) << 4)));
            a1 = __builtin_amdgcn_mfma_f32_16x16x32_bf16(f1, xf[ks], a1, 0, 0, 0);
        }
        // p = exp(sim) (|sim|<=1 -> no max pass), mask, pack
        unsigned short pw[8];
        #pragma unroll
        for (int r = 0; r < 4; ++r) {
            const int n0 = c * 32 + g * 4 + r;
            const float p0 = (n0 < len) ? __expf(a0[r]) : 0.f;
            ssum += p0; pw[r] = f2bf(p0);
            const float p1 = (n0 + 16 < len) ? __expf(a1[r]) : 0.f;
            ssum += p1; pw[4 + r] = f2bf(p1);
        }
        pm[c][0] = (unsigned)pw[0] | ((unsigned)pw[1] << 16);
        pm[c][1] = (unsigned)pw[2] | ((unsigned)pw[3] << 16);
        pm[c][2] = (unsigned)pw[4] | ((unsigned)pw[5] << 16);
        pm[c][3] = (unsigned)pw[6] | ((unsigned)pw[7] << 16);
    }

    // ---- row sums (row l = w*16+lo held by lanes lo, lo+16, lo+32, lo+48) ----
    ssum += __shfl_xor(ssum, 16);
    ssum += __shfl_xor(ssum, 32);
    const float sinv = 1.0f / ssum;
    if (g == 0) sm.tbl[w * 16 + lo] = sinv;

    // ================= E phase (W stores interleaved) =================
    f32x4 e[16];
    #pragma unroll
    for (int i = 0; i < 16; ++i) e[i] = (f32x4){0.f, 0.f, 0.f, 0.f};

    float* Wrow = out + (size_t)BB * LL * DD
                + ((size_t)b * LL + l0 + w * 16 + lo) * (size_t)NN;

    #pragma unroll
    for (int c = 0; c < 16; ++c) {
        if (c == 0) asm volatile("s_waitcnt vmcnt(0)" ::: "memory");  // pe[0] landed
        else        asm volatile("s_waitcnt vmcnt(2)" ::: "memory");  // allow 2 W stores in flight
        __builtin_amdgcn_s_barrier();
        __builtin_amdgcn_sched_barrier(0);
        if (c < 15) {
            const char* src = peB + (c + 1) * 16384;
            char* dst = (char*)sm.u.pe[(c + 1) & 1];
            #pragma unroll
            for (int q = 0; q < 4; ++q)
                GLL16(src + q * 4096 + tid * 16, dst + q * 4096 + tid * 16);
        }
        // W stores for this chunk: full 128B line per row across the wave
        float4 v0, v1;
        v0.x = bflo(pm[c][0]) * sinv; v0.y = bfhi(pm[c][0]) * sinv;
        v0.z = bflo(pm[c][1]) * sinv; v0.w = bfhi(pm[c][1]) * sinv;
        v1.x = bflo(pm[c][2]) * sinv; v1.y = bfhi(pm[c][2]) * sinv;
        v1.z = bflo(pm[c][3]) * sinv; v1.w = bfhi(pm[c][3]) * sinv;
        *(float4*)(Wrow + c * 32 + g * 4)      = v0;
        *(float4*)(Wrow + c * 32 + 16 + g * 4) = v1;

        // E += p-frag · pe
        union { unsigned u[4]; bf16x8 v; } pf;
        pf.u[0] = pm[c][0]; pf.u[1] = pm[c][1];
        pf.u[2] = pm[c][2]; pf.u[3] = pm[c][3];
        const char* peL = (const char*)sm.u.pe[c & 1];
        #pragma unroll
        for (int df = 0; df < 16; ++df) {
            const bf16x8 bf = *(const bf16x8*)(peL +
                (((df * 16 + lo) * 64 + g * 16) ^ (lo << 4)));
            e[df] = __builtin_amdgcn_mfma_f32_16x16x32_bf16(pf.v, bf, e[df], 0, 0, 0);
        }
    }

    // ---- E epilogue: per-wave transpose through dead pn area, float4 stores ----
    float t4[4];
    #pragma unroll
    for (int r = 0; r < 4; ++r) t4[r] = sm.tbl[w * 16 + g * 4 + r];
    char* scr = (char*)sm.pn + w * 8192;       // 4 slabs of 1040B (pad kills conflicts)
    float* Eout = out + ((size_t)b * LL + l0 + w * 16) * DD;
    #pragma unroll
    for (int r = 0; r < 4; ++r) {
        #pragma unroll
        for (int df = 0; df < 16; ++df)
            *(float*)(scr + g * 1040 + (size_t)(df * 16 + lo) * 4) = e[df][r] * t4[r];
        #pragma unroll
        for (int it = 0; it < 4; ++it) {
            const float4 t = *(const float4*)(scr + it * 1040 + lane * 16);
            *(float4*)(Eout + (size_t)(it * 4 + r) * DD + lane * 4) = t;
        }
    }
}

extern "C" void kernel_launch(void* const* d_in, const int* in_sizes, int n_in,
                              void* d_out, int out_size, void* d_ws, size_t ws_size,
                              hipStream_t stream) {
    const float* X    = (const float*)d_in[0];
    const float* P    = (const float*)d_in[1];
    const int*   lens = (const int*)d_in[2];
    float*       out  = (float*)d_out;

    // workspace: pnI (4MB) | peI (4MB)
    char* pnI = (char*)d_ws;
    char* peI = (char*)d_ws + 4194304;

    hipLaunchKernelGGL(cda_prep, dim3(BB * NN / 4), dim3(256), 0, stream, P, pnI, peI);
    hipLaunchKernelGGL(cda_main, dim3(1024), dim3(256), 0, stream, X, pnI, peI, lens, out);
}